// Round 1
// baseline (228.880 us; speedup 1.0000x reference)
//
#include <hip/hip_runtime.h>
#include <hip/hip_bf16.h>
#include <stdint.h>

#define OUTN   8192
#define INN    8192
#define NGRP   64
#define BATCHN 64
#define BN     128
#define BK     128
#define KSPLIT 8
#define KCHUNK (INN / KSPLIT)   /* 1024 */
#define NITER  (KCHUNK / BK)    /* 8 */

typedef __attribute__((ext_vector_type(8))) short bf16x8;
typedef __attribute__((ext_vector_type(4))) float f32x4;
typedef __attribute__((ext_vector_type(4))) unsigned int u32x4;

__device__ __forceinline__ unsigned short f2bf(float f) {
  __hip_bfloat16 h = __float2bfloat16(f);
  return __builtin_bit_cast(unsigned short, h);
}
__device__ __forceinline__ float bf2f(unsigned short h) {
  unsigned int u = ((unsigned int)h) << 16;
  return __builtin_bit_cast(float, u);
}

// xsum[g][b] = sum over k in group g of bf16-rounded x[b][k]  (64x64 fp32, 16 KB in ws)
__global__ void qlin_prep(const float* __restrict__ x, float* __restrict__ xsum) {
  const int b = blockIdx.x;
  const int t = threadIdx.x;
  const float* xrow = x + (size_t)b * INN + t * 32;
  float s = 0.0f;
#pragma unroll
  for (int i = 0; i < 8; ++i) {
    float4 v = *(const float4*)(xrow + i * 4);
    s += bf2f(f2bf(v.x)) + bf2f(f2bf(v.y)) + bf2f(f2bf(v.z)) + bf2f(f2bf(v.w));
  }
  __shared__ float part[256];
  part[t] = s;
  __syncthreads();
  if (t < NGRP) {
    float g = part[4 * t] + part[4 * t + 1] + part[4 * t + 2] + part[4 * t + 3];
    xsum[t * BATCHN + b] = g;  // group (t) spans k in [128t, 128t+128) for row b
  }
}

__global__ __launch_bounds__(256, 2) void qlin_main(
    const float* __restrict__ x, const int* __restrict__ packed,
    const float* __restrict__ scales, const float* __restrict__ xsum,
    float* __restrict__ out) {
  const int bx    = blockIdx.x;
  const int ks    = bx & (KSPLIT - 1);
  const int ntile = bx >> 3;
  const int o0    = ntile * BN;
  const int g0    = ks * NITER;
  const int k0    = ks * KCHUNK;

  const int t    = threadIdx.x;
  const int lane = t & 63;
  const int w    = t >> 6;        // wave 0..3, owns N columns [w*32, w*32+32)
  const int l15  = lane & 15;
  const int quad = lane >> 4;

  __shared__ __align__(16) int            pk[BN][68];       // packed tile, +4 pad
  __shared__ __align__(16) unsigned short xt[BATCHN][136];  // x bf16 tile, +8 pad
  __shared__ __align__(16) float          st[BN][9];        // scales o x group
  __shared__ __align__(16) float          xs[NITER][BATCHN];

  // stage scales (128x8) and xsum (8x64) once
#pragma unroll
  for (int i = 0; i < 4; ++i) {
    int v = t * 4 + i;
    int ol = v >> 3, gl = v & 7;
    st[ol][gl] = scales[(size_t)(o0 + ol) * NGRP + g0 + gl];
  }
#pragma unroll
  for (int i = 0; i < 2; ++i) {
    int v = t * 2 + i;
    int gl = v >> 6, b = v & 63;
    xs[gl][b] = xsum[(g0 + gl) * BATCHN + b];
  }

  int4   pkr[8];
  float4 xr[8];

  auto load_tile = [&](int i) {
    const int kk2 = ks * (KCHUNK / 2) + i * (BK / 2);  // int32 col base in packed row
    const int* pbase = packed + (size_t)(o0 + (t >> 4)) * (INN / 2) + kk2 + (t & 15) * 4;
#pragma unroll
    for (int j = 0; j < 8; ++j)
      pkr[j] = *(const int4*)(pbase + (size_t)j * 16 * (INN / 2));
    const int kk = k0 + i * BK;
    const float* xbase = x + (size_t)(t >> 5) * INN + kk + (t & 31) * 4;
#pragma unroll
    for (int j = 0; j < 8; ++j)
      xr[j] = *(const float4*)(xbase + (size_t)j * 8 * INN);
  };

  auto store_tile = [&]() {
    const int prow = t >> 4, pcol = (t & 15) * 4;
#pragma unroll
    for (int j = 0; j < 8; ++j)
      *(int4*)&pk[prow + 16 * j][pcol] = pkr[j];
    const int xrow = t >> 5, xcol = (t & 31) * 4;
#pragma unroll
    for (int j = 0; j < 8; ++j) {
      ushort4 h;
      h.x = f2bf(xr[j].x); h.y = f2bf(xr[j].y);
      h.z = f2bf(xr[j].z); h.w = f2bf(xr[j].w);
      *(ushort4*)&xt[xrow + 8 * j][xcol] = h;
    }
  };

  f32x4 facc[4][2];
#pragma unroll
  for (int mt = 0; mt < 4; ++mt)
#pragma unroll
    for (int nt = 0; nt < 2; ++nt)
      facc[mt][nt] = (f32x4){0.f, 0.f, 0.f, 0.f};

  load_tile(0);

  for (int i = 0; i < NITER; ++i) {
    __syncthreads();              // LDS consumers of prev iter done
    store_tile();
    if (i + 1 < NITER) load_tile(i + 1);  // prefetch flies during compute below
    __syncthreads();              // tile visible

    f32x4 gacc[4][2];
#pragma unroll
    for (int mt = 0; mt < 4; ++mt)
#pragma unroll
      for (int nt = 0; nt < 2; ++nt)
        gacc[mt][nt] = (f32x4){0.f, 0.f, 0.f, 0.f};

#pragma unroll
    for (int kq = 0; kq < 4; ++kq) {
      bf16x8 af[4];
#pragma unroll
      for (int mt = 0; mt < 4; ++mt)
        af[mt] = *(const bf16x8*)&xt[mt * 16 + l15][kq * 32 + quad * 8];

      bf16x8 bfv[2];
#pragma unroll
      for (int nt = 0; nt < 2; ++nt) {
        int4 v4 = *(const int4*)&pk[w * 32 + nt * 16 + l15][kq * 16 + quad * 4];
        u32x4 bw;
        // byte v -> bf16 pair (128+lo | 128+hi): 0x4300 | nibble, exact in bf16
        bw.x = 0x43004300u | ((unsigned)v4.x & 0xFu) | (((unsigned)v4.x & 0xF0u) << 12);
        bw.y = 0x43004300u | ((unsigned)v4.y & 0xFu) | (((unsigned)v4.y & 0xF0u) << 12);
        bw.z = 0x43004300u | ((unsigned)v4.z & 0xFu) | (((unsigned)v4.z & 0xF0u) << 12);
        bw.w = 0x43004300u | ((unsigned)v4.w & 0xFu) | (((unsigned)v4.w & 0xF0u) << 12);
        bfv[nt] = __builtin_bit_cast(bf16x8, bw);
      }
#pragma unroll
      for (int mt = 0; mt < 4; ++mt)
#pragma unroll
        for (int nt = 0; nt < 2; ++nt)
          gacc[mt][nt] = __builtin_amdgcn_mfma_f32_16x16x32_bf16(
              af[mt], bfv[nt], gacc[mt][nt], 0, 0, 0);
    }

    // fold group i: y += s[o,g] * (S_g - 136 * xsum_g[b])
    float s0 = st[w * 32 + l15][i];
    float s1 = st[w * 32 + 16 + l15][i];
#pragma unroll
    for (int mt = 0; mt < 4; ++mt) {
      f32x4 xv = *(const f32x4*)&xs[i][mt * 16 + quad * 4];
#pragma unroll
      for (int r = 0; r < 4; ++r) {
        float t0 = gacc[mt][0][r] - 136.0f * xv[r];
        float t1 = gacc[mt][1][r] - 136.0f * xv[r];
        facc[mt][0][r] += s0 * t0;
        facc[mt][1][r] += s1 * t1;
      }
    }
  }

  // epilogue: split-K partials -> fp32 atomics (out zeroed by memset)
  const int obase = o0 + w * 32 + l15;
#pragma unroll
  for (int mt = 0; mt < 4; ++mt)
#pragma unroll
    for (int r = 0; r < 4; ++r) {
      int m = mt * 16 + quad * 4 + r;
#pragma unroll
      for (int nt = 0; nt < 2; ++nt)
        atomicAdd(&out[(size_t)m * OUTN + obase + nt * 16], facc[mt][nt][r]);
    }
}

extern "C" void kernel_launch(void* const* d_in, const int* in_sizes, int n_in,
                              void* d_out, int out_size, void* d_ws, size_t ws_size,
                              hipStream_t stream) {
  const float* x      = (const float*)d_in[0];
  const int*   packed = (const int*)d_in[1];
  const float* scales = (const float*)d_in[2];
  float* out  = (float*)d_out;
  float* xsum = (float*)d_ws;  // 64 groups x 64 batch fp32 = 16 KB

  hipMemsetAsync(d_out, 0, (size_t)out_size * sizeof(float), stream);
  qlin_prep<<<BATCHN, 256, 0, stream>>>(x, xsum);
  qlin_main<<<(OUTN / BN) * KSPLIT, 256, 0, stream>>>(x, packed, scales, xsum, out);
}

// Round 2
// 207.891 us; speedup vs baseline: 1.1010x; 1.1010x over previous
//
#include <hip/hip_runtime.h>
#include <hip/hip_bf16.h>
#include <stdint.h>

#define OUTN   8192
#define INN    8192
#define NGRP   64
#define BATCHN 64
#define BN     64
#define BK     128
#define KSPLIT 8
#define KCHUNK (INN / KSPLIT)   /* 1024 */
#define NITER  (KCHUNK / BK)    /* 8 */
#define OSZ    (BATCHN * OUTN)  /* 524288 floats = 2 MB */

typedef __attribute__((ext_vector_type(8))) short bf16x8;
typedef __attribute__((ext_vector_type(4))) float f32x4;
typedef __attribute__((ext_vector_type(4))) unsigned int u32x4;

__device__ __forceinline__ unsigned short f2bf(float f) {
  __hip_bfloat16 h = __float2bfloat16(f);
  return __builtin_bit_cast(unsigned short, h);
}
__device__ __forceinline__ float bf2f(unsigned short h) {
  unsigned int u = ((unsigned int)h) << 16;
  return __builtin_bit_cast(float, u);
}

// xsum[g][b] = sum over k in group g of bf16-rounded x[b][k]  (64x64 fp32)
__global__ void qlin_prep(const float* __restrict__ x, float* __restrict__ xsum) {
  const int b = blockIdx.x;
  const int t = threadIdx.x;
  const float* xrow = x + (size_t)b * INN + t * 32;
  float s = 0.0f;
#pragma unroll
  for (int i = 0; i < 8; ++i) {
    float4 v = *(const float4*)(xrow + i * 4);
    s += bf2f(f2bf(v.x)) + bf2f(f2bf(v.y)) + bf2f(f2bf(v.z)) + bf2f(f2bf(v.w));
  }
  __shared__ float part[256];
  part[t] = s;
  __syncthreads();
  if (t < NGRP) {
    float g = part[4 * t] + part[4 * t + 1] + part[4 * t + 2] + part[4 * t + 3];
    xsum[t * BATCHN + b] = g;
  }
}

// LDS strides (in elements)
#define PKS 17    /* pk_c row stride, dwords: 16 data + 1 pad */
#define XTS 136   /* xt row stride, ushorts: 128 data + 8 pad (272B, 16B-aligned) */

__global__ __launch_bounds__(256, 4) void qlin_main(
    const float* __restrict__ x, const int* __restrict__ packed,
    const float* __restrict__ scales, const float* __restrict__ xsum,
    float* __restrict__ out, float* __restrict__ part) {
  const int bx    = blockIdx.x;
  const int ks    = bx & (KSPLIT - 1);
  const int ntile = bx >> 3;
  const int o0    = ntile * BN;
  const int g0    = ks * NITER;

  const int t    = threadIdx.x;
  const int lane = t & 63;
  const int w    = t >> 6;        // wave 0..3, owns N columns [w*16, w*16+16)
  const int l15  = lane & 15;
  const int quad = lane >> 4;

  __shared__ __align__(16) unsigned int   pk_c[BN * PKS];      // 4.4 KB compressed bytes
  __shared__ __align__(16) unsigned short xt[BATCHN * XTS];    // 17.4 KB x bf16
  __shared__ __align__(16) float          st[BN][9];           // scales
  __shared__ __align__(16) float          xs[NITER][BATCHN];   // group x-sums

  // stage scales (64x8) and xsum (8x64) once
#pragma unroll
  for (int i = 0; i < 2; ++i) {
    int v = t * 2 + i;
    int ol = v >> 3, gl = v & 7;
    st[ol][gl] = scales[(size_t)(o0 + ol) * NGRP + g0 + gl];
    int gl2 = v >> 6, b2 = v & 63;
    xs[gl2][b2] = xsum[(g0 + gl2) * BATCHN + b2];
  }

  int4   pkr[4];
  float4 xr[8];

  const int prow = t >> 4, pcol = t & 15;   // packed: 16 lanes cover a 256B row
  const int xrow = t >> 5, xcol = t & 31;   // x: 32 lanes cover a 512B row

  auto load_tile = [&](int i) {
    const int kk2 = ks * (KCHUNK / 2) + i * (BK / 2);  // int col base in packed row
    const int* pbase = packed + (size_t)(o0 + prow) * (INN / 2) + kk2 + pcol * 4;
#pragma unroll
    for (int j = 0; j < 4; ++j)
      pkr[j] = *(const int4*)(pbase + (size_t)(16 * j) * (INN / 2));
    const int kk = ks * KCHUNK + i * BK;
    const float* xbase = x + (size_t)xrow * INN + kk + xcol * 4;
#pragma unroll
    for (int j = 0; j < 8; ++j)
      xr[j] = *(const float4*)(xbase + (size_t)(8 * j) * INN);
  };

  auto store_tile = [&]() {
#pragma unroll
    for (int j = 0; j < 4; ++j) {
      unsigned int c = (unsigned)pkr[j].x | ((unsigned)pkr[j].y << 8) |
                       ((unsigned)pkr[j].z << 16) | ((unsigned)pkr[j].w << 24);
      pk_c[(prow + 16 * j) * PKS + pcol] = c;
    }
#pragma unroll
    for (int j = 0; j < 8; ++j) {
      ushort4 h;
      h.x = f2bf(xr[j].x); h.y = f2bf(xr[j].y);
      h.z = f2bf(xr[j].z); h.w = f2bf(xr[j].w);
      *(ushort4*)&xt[(xrow + 8 * j) * XTS + xcol * 4] = h;
    }
  };

  f32x4 facc[4];
#pragma unroll
  for (int mt = 0; mt < 4; ++mt) facc[mt] = (f32x4){0.f, 0.f, 0.f, 0.f};

  load_tile(0);

  for (int i = 0; i < NITER; ++i) {
    __syncthreads();
    store_tile();
    if (i + 1 < NITER) load_tile(i + 1);  // flies during compute below
    __syncthreads();

    f32x4 gacc[4];
#pragma unroll
    for (int mt = 0; mt < 4; ++mt) gacc[mt] = (f32x4){0.f, 0.f, 0.f, 0.f};

#pragma unroll
    for (int kq = 0; kq < 4; ++kq) {
      bf16x8 af[4];
#pragma unroll
      for (int mt = 0; mt < 4; ++mt)
        af[mt] = *(const bf16x8*)&xt[(mt * 16 + l15) * XTS + kq * 32 + quad * 8];

      unsigned int c = pk_c[(w * 16 + l15) * PKS + kq * 4 + quad];
      u32x4 bw;
      bw.x = 0x43004300u | (c & 0xFu) | ((c & 0xF0u) << 12);
      bw.y = 0x43004300u | ((c >> 8) & 0xFu) | (((c >> 8) & 0xF0u) << 12);
      bw.z = 0x43004300u | ((c >> 16) & 0xFu) | (((c >> 16) & 0xF0u) << 12);
      bw.w = 0x43004300u | ((c >> 24) & 0xFu) | (((c >> 24) & 0xF0u) << 12);
      bf16x8 bfv = __builtin_bit_cast(bf16x8, bw);

#pragma unroll
      for (int mt = 0; mt < 4; ++mt)
        gacc[mt] = __builtin_amdgcn_mfma_f32_16x16x32_bf16(af[mt], bfv, gacc[mt], 0, 0, 0);
    }

    // fold group i: y += s[o,g] * (S_g - 136 * xsum_g[b])
    float s0 = st[w * 16 + l15][i];
#pragma unroll
    for (int mt = 0; mt < 4; ++mt) {
      f32x4 xv = *(const f32x4*)&xs[i][mt * 16 + quad * 4];
#pragma unroll
      for (int r = 0; r < 4; ++r)
        facc[mt][r] += s0 * (gacc[mt][r] - 136.0f * xv[r]);
    }
  }

  const int obase = o0 + w * 16 + l15;
  if (part) {
    float* pb = part + (size_t)ks * OSZ;
#pragma unroll
    for (int mt = 0; mt < 4; ++mt)
#pragma unroll
      for (int r = 0; r < 4; ++r) {
        int m = mt * 16 + quad * 4 + r;
        pb[(size_t)m * OUTN + obase] = facc[mt][r];
      }
  } else {
#pragma unroll
    for (int mt = 0; mt < 4; ++mt)
#pragma unroll
      for (int r = 0; r < 4; ++r) {
        int m = mt * 16 + quad * 4 + r;
        atomicAdd(&out[(size_t)m * OUTN + obase], facc[mt][r]);
      }
  }
}

__global__ void qlin_reduce(const float* __restrict__ part, float* __restrict__ out) {
  const size_t i = ((size_t)blockIdx.x * 256 + threadIdx.x) * 4;
  float4 s = *(const float4*)(part + i);
#pragma unroll
  for (int ks = 1; ks < KSPLIT; ++ks) {
    float4 v = *(const float4*)(part + (size_t)ks * OSZ + i);
    s.x += v.x; s.y += v.y; s.z += v.z; s.w += v.w;
  }
  *(float4*)(out + i) = s;
}

extern "C" void kernel_launch(void* const* d_in, const int* in_sizes, int n_in,
                              void* d_out, int out_size, void* d_ws, size_t ws_size,
                              hipStream_t stream) {
  const float* x      = (const float*)d_in[0];
  const int*   packed = (const int*)d_in[1];
  const float* scales = (const float*)d_in[2];
  float* out  = (float*)d_out;
  float* xsum = (float*)d_ws;                       // 16 KB
  const size_t part_off = 16384 / sizeof(float);
  const size_t need = 16384 + (size_t)KSPLIT * OSZ * sizeof(float);  // 16 KB + 16 MB
  float* part = (ws_size >= need) ? ((float*)d_ws + part_off) : nullptr;

  qlin_prep<<<BATCHN, 256, 0, stream>>>(x, xsum);
  if (!part)
    hipMemsetAsync(d_out, 0, (size_t)out_size * sizeof(float), stream);
  qlin_main<<<(OUTN / BN) * KSPLIT, 256, 0, stream>>>(x, packed, scales, xsum, out, part);
  if (part)
    qlin_reduce<<<OSZ / 4 / 256, 256, 0, stream>>>(part, out);
}